// Round 1
// baseline (780.128 us; speedup 1.0000x reference)
//
#include <hip/hip_runtime.h>

// Problem constants (fixed by setup_inputs)
#define M_DIM 4096
#define K_DIM 4096
#define N_DIM 12288
// GEMM tile
#define BM 256
#define BN 256
#define BK 64
#define NT (K_DIM / BK)   // 64 K-tiles

typedef __bf16 bf16x8  __attribute__((ext_vector_type(8)));
typedef float  floatx16 __attribute__((ext_vector_type(16)));

// ---------------- x fp32 -> bf16 ----------------
__global__ __launch_bounds__(256) void xcast_kernel(const float* __restrict__ x,
                                                    __bf16* __restrict__ xb) {
    int idx = blockIdx.x * 256 + threadIdx.x;      // each thread: 8 floats
    const float4* xv = (const float4*)x;
    float4 a = xv[idx * 2];
    float4 b = xv[idx * 2 + 1];
    bf16x8 o;
    o[0] = (__bf16)a.x; o[1] = (__bf16)a.y; o[2] = (__bf16)a.z; o[3] = (__bf16)a.w;
    o[4] = (__bf16)b.x; o[5] = (__bf16)b.y; o[6] = (__bf16)b.z; o[7] = (__bf16)b.w;
    ((bf16x8*)xb)[idx] = o;
}

// ---------------- W int4 -> bf16 dequant ----------------
__global__ __launch_bounds__(256) void dequant_kernel(const int* __restrict__ qw,
                                                      const float* __restrict__ scales,
                                                      const float* __restrict__ zeros,
                                                      __bf16* __restrict__ wb) {
    int idx = blockIdx.x * 256 + threadIdx.x;      // 0 .. N * (K/2/4)
    int n  = idx >> 9;                             // (K/2)/4 = 512 per row
    int jq = (idx & 511) << 2;                     // int32-column, step 4
    int g  = jq >> 6;                              // group = (2*j)/128 = j/64
    float s = scales[g * N_DIM + n];
    float z = zeros[g * N_DIM + n];
    int4 q = *(const int4*)(qw + (size_t)n * (K_DIM / 2) + jq);
    bf16x8 o;
    o[0] = (__bf16)(((float)(q.x & 15)        - z) * s);
    o[1] = (__bf16)(((float)((q.x >> 4) & 15) - z) * s);
    o[2] = (__bf16)(((float)(q.y & 15)        - z) * s);
    o[3] = (__bf16)(((float)((q.y >> 4) & 15) - z) * s);
    o[4] = (__bf16)(((float)(q.z & 15)        - z) * s);
    o[5] = (__bf16)(((float)((q.z >> 4) & 15) - z) * s);
    o[6] = (__bf16)(((float)(q.w & 15)        - z) * s);
    o[7] = (__bf16)(((float)((q.w >> 4) & 15) - z) * s);
    *(bf16x8*)(wb + (size_t)n * K_DIM + (size_t)jq * 2) = o;
}

// ---------------- bf16 GEMM: C[M,N] = A[M,K] * B[N,K]^T + bias ----------------
// 256x256 tile, BK=64, 8 waves (2 M-halves x 4 N-quarters), double-buffered
// 128 KiB LDS, 8-phase-style schedule: 4 quadrant phases per K-tile, one
// half-stage (2 global_load_lds) issued per phase for tile t+1, counted
// s_waitcnt vmcnt(4)/vmcnt(2) (never 0 in the loop), s_setprio around MFMA.
// Per-wave staging covers exactly the LDS regions that wave reads, so each
// wave's vmcnt counter tracks its own dependencies; barriers union the
// guarantees across waves.
// Swizzle g(row) = (row&7) ^ (((row>>3)&3)<<1) carried over (verified).
__global__ __launch_bounds__(512, 2) void gemm_kernel(const __bf16* __restrict__ A,
                                                      const __bf16* __restrict__ B,
                                                      const float* __restrict__ bias,
                                                      float* __restrict__ C) {
    __shared__ __bf16 As[2][BM * BK];   // 2 x 32 KB
    __shared__ __bf16 Bs[2][BN * BK];   // 2 x 32 KB

    const int tid  = threadIdx.x;
    const int wave = tid >> 6;           // 0..7
    const int lane = tid & 63;
    const int l32  = lane & 31;
    const int half = lane >> 5;
    const int side = wave >> 2;          // A M-half: 0 -> rows 0..127, 1 -> 128..255
    const int aw   = wave & 3;           // N-quarter index
    const int wm   = side * 128;
    const int wn   = aw * 64;
    const int bm0  = blockIdx.x * BM;    // x = M tiles: consecutive blocks share B
    const int bn0  = blockIdx.y * BN;

    const int rowInChunk = lane >> 3;    // 0..7 within an 8-row chunk
    const int slot       = lane & 7;
    const int gread      = (l32 & 7) ^ (((l32 >> 3) & 3) << 1);

    // Stage chunk ids (chunk = 8 rows x 64 k = 1 KiB, one gload per wave):
    // A: phase-1 pair covers this wave's quarter-rows read in phases 1-2;
    //    phase-4 pair covers rows read in phases 3-4.
    const int ca0 = side * 16 + aw * 2;        // A chunks: ca0, ca0+1
    const int ca1 = side * 16 + 8 + aw * 2;    // A chunks: ca1, ca1+1
    const int cb  = aw * 8 + side * 4;         // B chunks: cb..cb+3

    // Per-lane global sources (element offsets; add k0 per tile).
    #define SRCKEY(c) (slot ^ rowInChunk ^ (((c) & 3) << 1))
    const __bf16* sA0 = A + (size_t)(bm0 + (ca0    ) * 8 + rowInChunk) * K_DIM + SRCKEY(ca0    ) * 8;
    const __bf16* sA1 = A + (size_t)(bm0 + (ca0 + 1) * 8 + rowInChunk) * K_DIM + SRCKEY(ca0 + 1) * 8;
    const __bf16* sA2 = A + (size_t)(bm0 + (ca1    ) * 8 + rowInChunk) * K_DIM + SRCKEY(ca1    ) * 8;
    const __bf16* sA3 = A + (size_t)(bm0 + (ca1 + 1) * 8 + rowInChunk) * K_DIM + SRCKEY(ca1 + 1) * 8;
    const __bf16* sB0 = B + (size_t)(bn0 + (cb     ) * 8 + rowInChunk) * K_DIM + SRCKEY(cb     ) * 8;
    const __bf16* sB1 = B + (size_t)(bn0 + (cb  + 1) * 8 + rowInChunk) * K_DIM + SRCKEY(cb  + 1) * 8;
    const __bf16* sB2 = B + (size_t)(bn0 + (cb  + 2) * 8 + rowInChunk) * K_DIM + SRCKEY(cb  + 2) * 8;
    const __bf16* sB3 = B + (size_t)(bn0 + (cb  + 3) * 8 + rowInChunk) * K_DIM + SRCKEY(cb  + 3) * 8;

    const int dA0 = (ca0    ) * 512, dA1 = (ca0 + 1) * 512;
    const int dA2 = (ca1    ) * 512, dA3 = (ca1 + 1) * 512;
    const int dB0 = (cb     ) * 512, dB1 = (cb  + 1) * 512;
    const int dB2 = (cb  + 2) * 512, dB3 = (cb  + 3) * 512;

    #define GLOAD(G, L) __builtin_amdgcn_global_load_lds( \
        (const __attribute__((address_space(1))) void*)(G), \
        (__attribute__((address_space(3))) void*)(L), 16, 0, 0)

    // Read-address constants (element offsets into a [256][64] buffer).
    const int rA0 = (wm +  0 + l32) * BK;
    const int rA1 = (wm + 32 + l32) * BK;
    const int rA2 = (wm + 64 + l32) * BK;
    const int rA3 = (wm + 96 + l32) * BK;
    const int rB0 = (wn +  0 + l32) * BK;
    const int rB1 = (wn + 32 + l32) * BK;
    const int ko0 = ((0 * 2 + half) ^ gread) << 3;
    const int ko1 = ((1 * 2 + half) ^ gread) << 3;
    const int ko2 = ((2 * 2 + half) ^ gread) << 3;
    const int ko3 = ((3 * 2 + half) ^ gread) << 3;

    #define RD(P, R, KO) (*(const bf16x8*)((P) + (R) + (KO)))
    #define MF(AF, BF, ACC) __builtin_amdgcn_mfma_f32_32x32x16_bf16((AF), (BF), (ACC), 0, 0, 0)

    floatx16 acc00 = {}, acc01 = {}, acc10 = {}, acc11 = {};
    floatx16 acc20 = {}, acc21 = {}, acc30 = {}, acc31 = {};

    // Prologue: stage tile 0, in deadline order (A-q0, B, A-q1).
    GLOAD(sA0, &As[0][dA0]); GLOAD(sA1, &As[0][dA1]);
    GLOAD(sB0, &Bs[0][dB0]); GLOAD(sB1, &Bs[0][dB1]);
    GLOAD(sB2, &Bs[0][dB2]); GLOAD(sB3, &Bs[0][dB3]);
    GLOAD(sA2, &As[0][dA2]); GLOAD(sA3, &As[0][dA3]);
    asm volatile("s_waitcnt vmcnt(2)" ::: "memory");   // A-q0 + B landed; A-q1 may fly
    __builtin_amdgcn_s_barrier();

    for (int kt = 0; kt < NT; ++kt) {
        const int cur = kt & 1;
        const int nxt = cur ^ 1;
        const int k0n = ((kt + 1) & (NT - 1)) * BK;    // last iter wraps (harmless)
        const __bf16* Ac = &As[cur][0];
        const __bf16* Bc = &Bs[cur][0];

        // ---- phase 1: quadrant (m0,m1) x n0 ----
        GLOAD(sA0 + k0n, &As[nxt][dA0]);
        GLOAD(sA1 + k0n, &As[nxt][dA1]);
        bf16x8 a0_0 = RD(Ac, rA0, ko0), a0_1 = RD(Ac, rA0, ko1), a0_2 = RD(Ac, rA0, ko2), a0_3 = RD(Ac, rA0, ko3);
        bf16x8 a1_0 = RD(Ac, rA1, ko0), a1_1 = RD(Ac, rA1, ko1), a1_2 = RD(Ac, rA1, ko2), a1_3 = RD(Ac, rA1, ko3);
        bf16x8 b0_0 = RD(Bc, rB0, ko0), b0_1 = RD(Bc, rB0, ko1), b0_2 = RD(Bc, rB0, ko2), b0_3 = RD(Bc, rB0, ko3);
        __builtin_amdgcn_s_barrier();
        __builtin_amdgcn_s_setprio(1);
        acc00 = MF(a0_0, b0_0, acc00); acc10 = MF(a1_0, b0_0, acc10);
        acc00 = MF(a0_1, b0_1, acc00); acc10 = MF(a1_1, b0_1, acc10);
        acc00 = MF(a0_2, b0_2, acc00); acc10 = MF(a1_2, b0_2, acc10);
        acc00 = MF(a0_3, b0_3, acc00); acc10 = MF(a1_3, b0_3, acc10);
        __builtin_amdgcn_s_setprio(0);
        __builtin_amdgcn_s_barrier();

        // ---- phase 2: quadrant (m0,m1) x n1 (reuse A regs) ----
        GLOAD(sB0 + k0n, &Bs[nxt][dB0]);
        GLOAD(sB1 + k0n, &Bs[nxt][dB1]);
        bf16x8 b1_0 = RD(Bc, rB1, ko0), b1_1 = RD(Bc, rB1, ko1), b1_2 = RD(Bc, rB1, ko2), b1_3 = RD(Bc, rB1, ko3);
        __builtin_amdgcn_s_barrier();
        __builtin_amdgcn_s_setprio(1);
        acc01 = MF(a0_0, b1_0, acc01); acc11 = MF(a1_0, b1_0, acc11);
        acc01 = MF(a0_1, b1_1, acc01); acc11 = MF(a1_1, b1_1, acc11);
        acc01 = MF(a0_2, b1_2, acc01); acc11 = MF(a1_2, b1_2, acc11);
        acc01 = MF(a0_3, b1_3, acc01); acc11 = MF(a1_3, b1_3, acc11);
        __builtin_amdgcn_s_setprio(0);
        // Mid-tile counted wait: guarantees prev-tile phase-4 A-q1 loads (this
        // tile's A rows 64..127 per side) landed before phase-3 reads them.
        asm volatile("s_waitcnt vmcnt(4)" ::: "memory");
        __builtin_amdgcn_s_barrier();

        // ---- phase 3: quadrant (m2,m3) x n1 (reuse B1 regs) ----
        GLOAD(sB2 + k0n, &Bs[nxt][dB2]);
        GLOAD(sB3 + k0n, &Bs[nxt][dB3]);
        bf16x8 a2_0 = RD(Ac, rA2, ko0), a2_1 = RD(Ac, rA2, ko1), a2_2 = RD(Ac, rA2, ko2), a2_3 = RD(Ac, rA2, ko3);
        bf16x8 a3_0 = RD(Ac, rA3, ko0), a3_1 = RD(Ac, rA3, ko1), a3_2 = RD(Ac, rA3, ko2), a3_3 = RD(Ac, rA3, ko3);
        __builtin_amdgcn_s_barrier();
        __builtin_amdgcn_s_setprio(1);
        acc21 = MF(a2_0, b1_0, acc21); acc31 = MF(a3_0, b1_0, acc31);
        acc21 = MF(a2_1, b1_1, acc21); acc31 = MF(a3_1, b1_1, acc31);
        acc21 = MF(a2_2, b1_2, acc21); acc31 = MF(a3_2, b1_2, acc31);
        acc21 = MF(a2_3, b1_3, acc21); acc31 = MF(a3_3, b1_3, acc31);
        __builtin_amdgcn_s_setprio(0);
        __builtin_amdgcn_s_barrier();

        // ---- phase 4: quadrant (m2,m3) x n0 (reuse A23 + B0 regs, no ds_read) ----
        GLOAD(sA2 + k0n, &As[nxt][dA2]);
        GLOAD(sA3 + k0n, &As[nxt][dA3]);
        __builtin_amdgcn_s_setprio(1);
        acc20 = MF(a2_0, b0_0, acc20); acc30 = MF(a3_0, b0_0, acc30);
        acc20 = MF(a2_1, b0_1, acc20); acc30 = MF(a3_1, b0_1, acc30);
        acc20 = MF(a2_2, b0_2, acc20); acc30 = MF(a3_2, b0_2, acc30);
        acc20 = MF(a2_3, b0_3, acc20); acc30 = MF(a3_3, b0_3, acc30);
        __builtin_amdgcn_s_setprio(0);
        // Boundary counted wait: next tile's A-q0 + all B landed; only the 2
        // phase-4 A-q1 loads (needed at next phase 3) may remain in flight.
        asm volatile("s_waitcnt vmcnt(2)" ::: "memory");
        __builtin_amdgcn_s_barrier();
    }

    // Epilogue: 32x32 C/D layout: col = lane&31, row = (reg&3)+8*(reg>>2)+4*half.
    #define EPI(ACC, MI, NI) { \
        const int col = bn0 + wn + (NI) * 32 + l32; \
        const float bv = bias[col]; \
        _Pragma("unroll") \
        for (int r = 0; r < 16; ++r) { \
            const int row = bm0 + wm + (MI) * 32 + half * 4 + (r & 3) + 8 * (r >> 2); \
            C[(size_t)row * N_DIM + col] = ACC[r] + bv; \
        } }
    EPI(acc00, 0, 0); EPI(acc01, 0, 1);
    EPI(acc10, 1, 0); EPI(acc11, 1, 1);
    EPI(acc20, 2, 0); EPI(acc21, 2, 1);
    EPI(acc30, 3, 0); EPI(acc31, 3, 1);
}

extern "C" void kernel_launch(void* const* d_in, const int* in_sizes, int n_in,
                              void* d_out, int out_size, void* d_ws, size_t ws_size,
                              hipStream_t stream) {
    const float* x      = (const float*)d_in[0];
    const int*   qw     = (const int*)d_in[1];
    const float* scales = (const float*)d_in[2];
    const float* zeros  = (const float*)d_in[3];
    const float* bias   = (const float*)d_in[4];
    float* out = (float*)d_out;

    // Workspace layout: [xb: M*K bf16 = 32 MiB][wb: N*K bf16 = 96 MiB] = 128 MiB
    __bf16* xb = (__bf16*)d_ws;
    __bf16* wb = (__bf16*)((char*)d_ws + (size_t)M_DIM * K_DIM * 2);

    xcast_kernel<<<(M_DIM * K_DIM / 8) / 256, 256, 0, stream>>>(x, xb);
    dequant_kernel<<<(N_DIM * (K_DIM / 2) / 4) / 256, 256, 0, stream>>>(qw, scales, zeros, wb);

    dim3 grid(M_DIM / BM, N_DIM / BN);   // (16, 48): x = M tiles, share B in L2
    gemm_kernel<<<grid, 512, 0, stream>>>(xb, wb, bias, out);
}

// Round 2
// 729.067 us; speedup vs baseline: 1.0700x; 1.0700x over previous
//
#include <hip/hip_runtime.h>

// Problem constants (fixed by setup_inputs)
#define M_DIM 4096
#define K_DIM 4096
#define N_DIM 12288
// GEMM tile
#define BM 256
#define BN 256
#define BK 64
#define NT (K_DIM / BK)   // 64 K-tiles

typedef __bf16 bf16x8  __attribute__((ext_vector_type(8)));
typedef float  floatx16 __attribute__((ext_vector_type(16)));

// ---------------- x fp32 -> bf16 ----------------
__global__ __launch_bounds__(256) void xcast_kernel(const float* __restrict__ x,
                                                    __bf16* __restrict__ xb) {
    int idx = blockIdx.x * 256 + threadIdx.x;      // each thread: 8 floats
    const float4* xv = (const float4*)x;
    float4 a = xv[idx * 2];
    float4 b = xv[idx * 2 + 1];
    bf16x8 o;
    o[0] = (__bf16)a.x; o[1] = (__bf16)a.y; o[2] = (__bf16)a.z; o[3] = (__bf16)a.w;
    o[4] = (__bf16)b.x; o[5] = (__bf16)b.y; o[6] = (__bf16)b.z; o[7] = (__bf16)b.w;
    ((bf16x8*)xb)[idx] = o;
}

// ---------------- W int4 -> bf16 dequant ----------------
__global__ __launch_bounds__(256) void dequant_kernel(const int* __restrict__ qw,
                                                      const float* __restrict__ scales,
                                                      const float* __restrict__ zeros,
                                                      __bf16* __restrict__ wb) {
    int idx = blockIdx.x * 256 + threadIdx.x;      // 0 .. N * (K/2/4)
    int n  = idx >> 9;                             // (K/2)/4 = 512 per row
    int jq = (idx & 511) << 2;                     // int32-column, step 4
    int g  = jq >> 6;                              // group = (2*j)/128 = j/64
    float s = scales[g * N_DIM + n];
    float z = zeros[g * N_DIM + n];
    int4 q = *(const int4*)(qw + (size_t)n * (K_DIM / 2) + jq);
    bf16x8 o;
    o[0] = (__bf16)(((float)(q.x & 15)        - z) * s);
    o[1] = (__bf16)(((float)((q.x >> 4) & 15) - z) * s);
    o[2] = (__bf16)(((float)(q.y & 15)        - z) * s);
    o[3] = (__bf16)(((float)((q.y >> 4) & 15) - z) * s);
    o[4] = (__bf16)(((float)(q.z & 15)        - z) * s);
    o[5] = (__bf16)(((float)((q.z >> 4) & 15) - z) * s);
    o[6] = (__bf16)(((float)(q.w & 15)        - z) * s);
    o[7] = (__bf16)(((float)((q.w >> 4) & 15) - z) * s);
    *(bf16x8*)(wb + (size_t)n * K_DIM + (size_t)jq * 2) = o;
}

// ---------------- bf16 GEMM: C[M,N] = A[M,K] * B[N,K]^T + bias ----------------
// 256x256 tile, BK=64, 8 waves (2M x 4N, each 128x64), double-buffered LDS.
// Key change vs round 1: LDS is half-K subtiled [dbuf][khalf][256 rows][32 el]
// -> row stride 64 B (row&1 enters bank index), 2-bit slot swizzle
// swz(row) = ((row>>1)^(row>>3))&3 applied on global source + read address
// (DMA dest stays linear). Targets the 37.8M bank-conflict counter.
// Per-k-step phases: 6 ds_read_b128 + 8 independent MFMAs per phase.
// Staging: per wave 4 gloads per half-tile (A rc, A rc+1, B rc, B rc+1 with
// rc = 2*wave), issued on phases 1 (half0 of t+1) and 3 (half1 of t+1);
// s_waitcnt vmcnt(4) twice per tile (never 0), barrier extends cross-wave.
__global__ __launch_bounds__(512, 2) void gemm_kernel(const __bf16* __restrict__ A,
                                                      const __bf16* __restrict__ B,
                                                      const float* __restrict__ bias,
                                                      float* __restrict__ C) {
    // [dbuf][khalf][256][32] elements, flattened. 64 KB each.
    __shared__ __bf16 As[2 * 2 * 256 * 32];
    __shared__ __bf16 Bs[2 * 2 * 256 * 32];

    const int tid  = threadIdx.x;
    const int wave = tid >> 6;           // 0..7
    const int lane = tid & 63;
    const int l32  = lane & 31;
    const int half = lane >> 5;
    const int side = wave >> 2;          // A M-half
    const int aw   = wave & 3;           // N-quarter
    const int wm   = side * 128;
    const int wn   = aw * 64;
    const int bm0  = blockIdx.x * BM;    // x = M tiles: consecutive blocks share B
    const int bn0  = blockIdx.y * BN;

    // ---- staging lane constants ----
    // One gload = 64 lanes x 16 B = 16 rows x 32 elems (one khalf chunk).
    // Lane i -> LDS (row = rc*16 + (i>>2), phys slot = i&3). Global source
    // column = h*32 + ((i&3) ^ swz(row))*8 so phys slot p holds logical
    // slot p ^ swz(row). swz(row) = ((row>>1)^(row>>3))&3 =
    // bswz(lane) ^ ((rc&1)<<1) with bswz = ((lane>>3)&3) ^ ((lane>>5)&3).
    const int r16  = lane >> 2;
    const int sl4  = lane & 3;
    const int bswz = ((lane >> 3) & 3) ^ ((lane >> 5) & 3);
    const int key0 = sl4 ^ bswz;               // rc even
    const int key1 = key0 ^ 2;                 // rc odd
    const __bf16* sA0 = A + (size_t)(bm0 + 32 * wave +      r16) * K_DIM + key0 * 8;
    const __bf16* sA1 = A + (size_t)(bm0 + 32 * wave + 16 + r16) * K_DIM + key1 * 8;
    const __bf16* sB0 = B + (size_t)(bn0 + 32 * wave +      r16) * K_DIM + key0 * 8;
    const __bf16* sB1 = B + (size_t)(bn0 + 32 * wave + 16 + r16) * K_DIM + key1 * 8;
    const int dst0 = wave * 1024;              // rc0*512
    const int dst1 = wave * 1024 + 512;        // rc1*512

    #define GLOAD(G, L) __builtin_amdgcn_global_load_lds( \
        (const __attribute__((address_space(1))) void*)(G), \
        (__attribute__((address_space(3))) void*)(L), 16, 0, 0)

    // ---- read-side constants ----
    // Phase ks reads logical k = ks*16 + half*8 + j: khalf h = ks>>1,
    // logical slot s0 = ((ks&1)<<1)|half, phys slot = s0 ^ swz(row).
    const int swzr = ((l32 >> 1) ^ (l32 >> 3)) & 3;
    const int koE  = ((half)     ^ swzr) << 3;   // even ks (s0 = half)
    const int koO  = ((2 | half) ^ swzr) << 3;   // odd ks  (s0 = 2|half)
    const int rA0 = (wm +  0 + l32) * 32;
    const int rA1 = (wm + 32 + l32) * 32;
    const int rA2 = (wm + 64 + l32) * 32;
    const int rA3 = (wm + 96 + l32) * 32;
    const int rB0 = (wn +  0 + l32) * 32;
    const int rB1 = (wn + 32 + l32) * 32;

    #define MF(AF, BF, ACC) __builtin_amdgcn_mfma_f32_32x32x16_bf16((AF), (BF), (ACC), 0, 0, 0)

    floatx16 acc00 = {}, acc01 = {}, acc10 = {}, acc11 = {};
    floatx16 acc20 = {}, acc21 = {}, acc30 = {}, acc31 = {};

    // Prologue: stage tile 0 (half0 then half1) -> 8 outstanding = steady state.
    GLOAD(sA0,      As + dst0);        GLOAD(sA1,      As + dst1);
    GLOAD(sB0,      Bs + dst0);        GLOAD(sB1,      Bs + dst1);
    GLOAD(sA0 + 32, As + 8192 + dst0); GLOAD(sA1 + 32, As + 8192 + dst1);
    GLOAD(sB0 + 32, Bs + 8192 + dst0); GLOAD(sB1 + 32, Bs + 8192 + dst1);
    asm volatile("s_waitcnt vmcnt(4)" ::: "memory");   // half0 of tile 0 landed
    __builtin_amdgcn_s_barrier();

    #define READS(HOFF, KO) \
        a0 = *(const bf16x8*)(As + curo + (HOFF) + rA0 + (KO)); \
        b0 = *(const bf16x8*)(Bs + curo + (HOFF) + rB0 + (KO)); \
        a1 = *(const bf16x8*)(As + curo + (HOFF) + rA1 + (KO)); \
        b1 = *(const bf16x8*)(Bs + curo + (HOFF) + rB1 + (KO)); \
        a2 = *(const bf16x8*)(As + curo + (HOFF) + rA2 + (KO)); \
        a3 = *(const bf16x8*)(As + curo + (HOFF) + rA3 + (KO));

    #define MFMAS \
        __builtin_amdgcn_s_setprio(1); \
        acc00 = MF(a0, b0, acc00); acc10 = MF(a1, b0, acc10); \
        acc01 = MF(a0, b1, acc01); acc11 = MF(a1, b1, acc11); \
        acc20 = MF(a2, b0, acc20); acc21 = MF(a2, b1, acc21); \
        acc30 = MF(a3, b0, acc30); acc31 = MF(a3, b1, acc31); \
        __builtin_amdgcn_s_setprio(0);

    for (int kt = 0; kt < NT; ++kt) {
        const int curo = (kt & 1) * 16384;
        const int nxto = 16384 - curo;
        const int k0n  = ((kt + 1) & (NT - 1)) * BK;   // last iter wraps (dead data)
        bf16x8 a0, a1, a2, a3, b0, b1;

        // ---- phase 0: ks=0 (half0) ----
        READS(0, koE);
        __builtin_amdgcn_s_barrier();
        MFMAS;
        __builtin_amdgcn_s_barrier();

        // ---- phase 1: ks=1 (half0); stage half0 of t+1; drain half1 of t ----
        READS(0, koO);
        GLOAD(sA0 + k0n, As + nxto + dst0); GLOAD(sA1 + k0n, As + nxto + dst1);
        GLOAD(sB0 + k0n, Bs + nxto + dst0); GLOAD(sB1 + k0n, Bs + nxto + dst1);
        asm volatile("s_waitcnt vmcnt(4)" ::: "memory");  // half1(t) landed (own)
        __builtin_amdgcn_s_barrier();                     // ... and cross-wave
        MFMAS;
        __builtin_amdgcn_s_barrier();

        // ---- phase 2: ks=2 (half1) ----
        READS(8192, koE);
        __builtin_amdgcn_s_barrier();
        MFMAS;
        __builtin_amdgcn_s_barrier();

        // ---- phase 3: ks=3 (half1); stage half1 of t+1; drain half0 of t+1 ----
        READS(8192, koO);
        GLOAD(sA0 + k0n + 32, As + nxto + 8192 + dst0);
        GLOAD(sA1 + k0n + 32, As + nxto + 8192 + dst1);
        GLOAD(sB0 + k0n + 32, Bs + nxto + 8192 + dst0);
        GLOAD(sB1 + k0n + 32, Bs + nxto + 8192 + dst1);
        asm volatile("s_waitcnt vmcnt(4)" ::: "memory");  // half0(t+1) landed (own)
        __builtin_amdgcn_s_barrier();                     // ... and cross-wave
        MFMAS;
        __builtin_amdgcn_s_barrier();
    }

    // Epilogue: 32x32 C/D layout: col = lane&31, row = (reg&3)+8*(reg>>2)+4*half.
    #define EPI(ACC, MI, NI) { \
        const int col = bn0 + wn + (NI) * 32 + l32; \
        const float bv = bias[col]; \
        _Pragma("unroll") \
        for (int r = 0; r < 16; ++r) { \
            const int row = bm0 + wm + (MI) * 32 + half * 4 + (r & 3) + 8 * (r >> 2); \
            C[(size_t)row * N_DIM + col] = ACC[r] + bv; \
        } }
    EPI(acc00, 0, 0); EPI(acc01, 0, 1);
    EPI(acc10, 1, 0); EPI(acc11, 1, 1);
    EPI(acc20, 2, 0); EPI(acc21, 2, 1);
    EPI(acc30, 3, 0); EPI(acc31, 3, 1);
}

extern "C" void kernel_launch(void* const* d_in, const int* in_sizes, int n_in,
                              void* d_out, int out_size, void* d_ws, size_t ws_size,
                              hipStream_t stream) {
    const float* x      = (const float*)d_in[0];
    const int*   qw     = (const int*)d_in[1];
    const float* scales = (const float*)d_in[2];
    const float* zeros  = (const float*)d_in[3];
    const float* bias   = (const float*)d_in[4];
    float* out = (float*)d_out;

    // Workspace layout: [xb: M*K bf16 = 32 MiB][wb: N*K bf16 = 96 MiB] = 128 MiB
    __bf16* xb = (__bf16*)d_ws;
    __bf16* wb = (__bf16*)((char*)d_ws + (size_t)M_DIM * K_DIM * 2);

    xcast_kernel<<<(M_DIM * K_DIM / 8) / 256, 256, 0, stream>>>(x, xb);
    dequant_kernel<<<(N_DIM * (K_DIM / 2) / 4) / 256, 256, 0, stream>>>(qw, scales, zeros, wb);

    dim3 grid(M_DIM / BM, N_DIM / BN);   // (16, 48)
    gemm_kernel<<<grid, 512, 0, stream>>>(xb, wb, bias, out);
}

// Round 4
// 727.092 us; speedup vs baseline: 1.0729x; 1.0027x over previous
//
#include <hip/hip_runtime.h>

// Problem constants (fixed by setup_inputs)
#define M_DIM 4096
#define K_DIM 4096
#define N_DIM 12288
// GEMM tile
#define BM 256
#define BN 256
#define BK 64
#define NT (K_DIM / BK)   // 64 K-tiles
#define HALF 8192         // elements per k-half buffer (256 rows x 32)
#define BUF  16384        // elements per full-tile buffer (2 halves)

typedef __bf16 bf16x8  __attribute__((ext_vector_type(8)));
typedef float  floatx16 __attribute__((ext_vector_type(16)));

// ---------------- x fp32 -> bf16 ----------------
__global__ __launch_bounds__(256) void xcast_kernel(const float* __restrict__ x,
                                                    __bf16* __restrict__ xb) {
    int idx = blockIdx.x * 256 + threadIdx.x;      // each thread: 8 floats
    const float4* xv = (const float4*)x;
    float4 a = xv[idx * 2];
    float4 b = xv[idx * 2 + 1];
    bf16x8 o;
    o[0] = (__bf16)a.x; o[1] = (__bf16)a.y; o[2] = (__bf16)a.z; o[3] = (__bf16)a.w;
    o[4] = (__bf16)b.x; o[5] = (__bf16)b.y; o[6] = (__bf16)b.z; o[7] = (__bf16)b.w;
    ((bf16x8*)xb)[idx] = o;
}

// ---------------- W int4 -> bf16 dequant ----------------
__global__ __launch_bounds__(256) void dequant_kernel(const int* __restrict__ qw,
                                                      const float* __restrict__ scales,
                                                      const float* __restrict__ zeros,
                                                      __bf16* __restrict__ wb) {
    int idx = blockIdx.x * 256 + threadIdx.x;      // 0 .. N * (K/2/4)
    int n  = idx >> 9;                             // (K/2)/4 = 512 per row
    int jq = (idx & 511) << 2;                     // int32-column, step 4
    int g  = jq >> 6;                              // group = (2*j)/128 = j/64
    float s = scales[g * N_DIM + n];
    float z = zeros[g * N_DIM + n];
    int4 q = *(const int4*)(qw + (size_t)n * (K_DIM / 2) + jq);
    bf16x8 o;
    o[0] = (__bf16)(((float)(q.x & 15)        - z) * s);
    o[1] = (__bf16)(((float)((q.x >> 4) & 15) - z) * s);
    o[2] = (__bf16)(((float)(q.y & 15)        - z) * s);
    o[3] = (__bf16)(((float)((q.y >> 4) & 15) - z) * s);
    o[4] = (__bf16)(((float)(q.z & 15)        - z) * s);
    o[5] = (__bf16)(((float)((q.z >> 4) & 15) - z) * s);
    o[6] = (__bf16)(((float)(q.w & 15)        - z) * s);
    o[7] = (__bf16)(((float)((q.w >> 4) & 15) - z) * s);
    *(bf16x8*)(wb + (size_t)n * K_DIM + (size_t)jq * 2) = o;
}

// ---------------- bf16 GEMM: C[M,N] = A[M,K] * B[N,K]^T + bias ----------------
// 256x256 tile, BK=64, 8 waves (2M x 4N, each 128x64).
// LDS layout identical to round 2 (verified conflict-free reads): per operand
// 4 half-buffers of [256 rows][32 el]; half s lives at (s>>1 &1)*BUF +
// (s&1)*HALF. Swizzle: phys 16B-slot = logical ^ swz(row),
// swz(row) = ((row>>1)^(row>>3))&3, applied on global source + read address.
// Schedule (m201 phase grain): 2 phases per K-tile, each =
//   [12 ds_read_b128 (one k-half, both k-steps)] [4 global_load_lds stage]
//   [s_waitcnt vmcnt(8)] [barrier] [setprio1; 16 MFMA; setprio0] [barrier]
// Ring staging: phase p computes half p, stages half p+3 (slot (p+3)&3);
// vmcnt(8) at phase p retires half p+1 -> next phase's data guaranteed one
// phase early; barrier extends the guarantee cross-wave. Never drains to 0.
__global__ __launch_bounds__(512, 2) void gemm_kernel(const __bf16* __restrict__ A,
                                                      const __bf16* __restrict__ B,
                                                      const float* __restrict__ bias,
                                                      float* __restrict__ C) {
    __shared__ __bf16 As[2 * BUF];   // 64 KB
    __shared__ __bf16 Bs[2 * BUF];   // 64 KB

    const int tid  = threadIdx.x;
    const int wave = tid >> 6;           // 0..7
    const int lane = tid & 63;
    const int l32  = lane & 31;
    const int half = lane >> 5;
    const int side = wave >> 2;          // A M-half
    const int aw   = wave & 3;           // N-quarter
    const int wm   = side * 128;
    const int wn   = aw * 64;

    // XCD-aware bijective swizzle: 768 blocks, 96 per XCD = 6 N-columns x 16 M.
    const int bid = blockIdx.y * 16 + blockIdx.x;   // linear id (x fastest)
    const int sw  = (bid & 7) * 96 + (bid >> 3);
    const int bm0 = (sw & 15) * BM;                  // M fastest within chunk
    const int bn0 = (sw >> 4) * BN;

    // ---- staging lane constants ----
    const int r16  = lane >> 2;
    const int sl4  = lane & 3;
    const int bswz = ((lane >> 3) & 3) ^ ((lane >> 5) & 3);
    const int key0 = sl4 ^ bswz;               // rows 32w..32w+15
    const int key1 = key0 ^ 2;                 // rows 32w+16..32w+31
    const __bf16* sA0 = A + (size_t)(bm0 + 32 * wave +      r16) * K_DIM + key0 * 8;
    const __bf16* sA1 = A + (size_t)(bm0 + 32 * wave + 16 + r16) * K_DIM + key1 * 8;
    const __bf16* sB0 = B + (size_t)(bn0 + 32 * wave +      r16) * K_DIM + key0 * 8;
    const __bf16* sB1 = B + (size_t)(bn0 + 32 * wave + 16 + r16) * K_DIM + key1 * 8;
    const int dst0 = wave * 1024;
    const int dst1 = wave * 1024 + 512;

    #define GLOAD(G, L) __builtin_amdgcn_global_load_lds( \
        (const __attribute__((address_space(1))) void*)(G), \
        (__attribute__((address_space(3))) void*)(L), 16, 0, 0)

    // Stage one k-half (col offset CS elements) into half-buffer at LDS offset HO.
    #define STAGE(CS, HO) \
        GLOAD(sA0 + (CS), As + (HO) + dst0); GLOAD(sA1 + (CS), As + (HO) + dst1); \
        GLOAD(sB0 + (CS), Bs + (HO) + dst0); GLOAD(sB1 + (CS), Bs + (HO) + dst1);

    // ---- read-side constants ----
    const int swzr = ((l32 >> 1) ^ (l32 >> 3)) & 3;
    const int koE  = ((half)     ^ swzr) << 3;   // k-step 0 within half
    const int koO  = ((2 | half) ^ swzr) << 3;   // k-step 1 within half
    const int rA0 = (wm +  0 + l32) * 32;
    const int rA1 = (wm + 32 + l32) * 32;
    const int rA2 = (wm + 64 + l32) * 32;
    const int rA3 = (wm + 96 + l32) * 32;
    const int rB0 = (wn +  0 + l32) * 32;
    const int rB1 = (wn + 32 + l32) * 32;

    #define MF(AF, BF, ACC) __builtin_amdgcn_mfma_f32_32x32x16_bf16((AF), (BF), (ACC), 0, 0, 0)

    floatx16 acc00 = {}, acc01 = {}, acc10 = {}, acc11 = {};
    floatx16 acc20 = {}, acc21 = {}, acc30 = {}, acc31 = {};

    // One fat phase: reads (12), stage (4), vmcnt(8), barrier, 16 MFMA, barrier.
    #define PHASE(HO, CS, SHO) { \
        bf16x8 a0e = *(const bf16x8*)(As + (HO) + rA0 + koE); \
        bf16x8 a1e = *(const bf16x8*)(As + (HO) + rA1 + koE); \
        bf16x8 a2e = *(const bf16x8*)(As + (HO) + rA2 + koE); \
        bf16x8 a3e = *(const bf16x8*)(As + (HO) + rA3 + koE); \
        bf16x8 b0e = *(const bf16x8*)(Bs + (HO) + rB0 + koE); \
        bf16x8 b1e = *(const bf16x8*)(Bs + (HO) + rB1 + koE); \
        bf16x8 a0o = *(const bf16x8*)(As + (HO) + rA0 + koO); \
        bf16x8 a1o = *(const bf16x8*)(As + (HO) + rA1 + koO); \
        bf16x8 a2o = *(const bf16x8*)(As + (HO) + rA2 + koO); \
        bf16x8 a3o = *(const bf16x8*)(As + (HO) + rA3 + koO); \
        bf16x8 b0o = *(const bf16x8*)(Bs + (HO) + rB0 + koO); \
        bf16x8 b1o = *(const bf16x8*)(Bs + (HO) + rB1 + koO); \
        STAGE(CS, SHO); \
        asm volatile("s_waitcnt vmcnt(8)" ::: "memory"); \
        __builtin_amdgcn_s_barrier(); \
        __builtin_amdgcn_s_setprio(1); \
        acc00 = MF(a0e, b0e, acc00); acc10 = MF(a1e, b0e, acc10); \
        acc01 = MF(a0e, b1e, acc01); acc11 = MF(a1e, b1e, acc11); \
        acc20 = MF(a2e, b0e, acc20); acc21 = MF(a2e, b1e, acc21); \
        acc30 = MF(a3e, b0e, acc30); acc31 = MF(a3e, b1e, acc31); \
        acc00 = MF(a0o, b0o, acc00); acc10 = MF(a1o, b0o, acc10); \
        acc01 = MF(a0o, b1o, acc01); acc11 = MF(a1o, b1o, acc11); \
        acc20 = MF(a2o, b0o, acc20); acc21 = MF(a2o, b1o, acc21); \
        acc30 = MF(a3o, b0o, acc30); acc31 = MF(a3o, b1o, acc31); \
        __builtin_amdgcn_s_setprio(0); \
        __builtin_amdgcn_s_barrier(); }

    // Prologue: stage halves 0,1,2 (12 loads); vmcnt(8) => half 0 landed; barrier.
    STAGE(0,  0);        // s=0: tile0 h0 -> buf0+0
    STAGE(32, HALF);     // s=1: tile0 h1 -> buf0+HALF
    STAGE(64, BUF);      // s=2: tile1 h0 -> buf1+0
    asm volatile("s_waitcnt vmcnt(8)" ::: "memory");
    __builtin_amdgcn_s_barrier();

    for (int it = 0; it < NT / 2; ++it) {
        const int k64 = it * 128;                  // k-elems of tile 2*it
        // ---- tile 2*it (buffers at 0) ----
        PHASE(0,    (k64 +  96) & 4095, BUF + HALF);   // compute half 4it+0; stage 4it+3
        PHASE(HALF, (k64 + 128) & 4095, 0);            // compute half 4it+1; stage 4it+4
        // ---- tile 2*it+1 (buffers at BUF) ----
        PHASE(BUF,        (k64 + 160) & 4095, HALF);   // compute half 4it+2; stage 4it+5
        PHASE(BUF + HALF, (k64 + 192) & 4095, BUF);    // compute half 4it+3; stage 4it+6
    }

    // Epilogue: 32x32 C/D layout: col = lane&31, row = (reg&3)+8*(reg>>2)+4*half.
    #define EPI(ACC, MI, NI) { \
        const int col = bn0 + wn + (NI) * 32 + l32; \
        const float bv = bias[col]; \
        _Pragma("unroll") \
        for (int r = 0; r < 16; ++r) { \
            const int row = bm0 + wm + (MI) * 32 + half * 4 + (r & 3) + 8 * (r >> 2); \
            C[(size_t)row * N_DIM + col] = ACC[r] + bv; \
        } }
    EPI(acc00, 0, 0); EPI(acc01, 0, 1);
    EPI(acc10, 1, 0); EPI(acc11, 1, 1);
    EPI(acc20, 2, 0); EPI(acc21, 2, 1);
    EPI(acc30, 3, 0); EPI(acc31, 3, 1);
}

extern "C" void kernel_launch(void* const* d_in, const int* in_sizes, int n_in,
                              void* d_out, int out_size, void* d_ws, size_t ws_size,
                              hipStream_t stream) {
    const float* x      = (const float*)d_in[0];
    const int*   qw     = (const int*)d_in[1];
    const float* scales = (const float*)d_in[2];
    const float* zeros  = (const float*)d_in[3];
    const float* bias   = (const float*)d_in[4];
    float* out = (float*)d_out;

    // Workspace layout: [xb: M*K bf16 = 32 MiB][wb: N*K bf16 = 96 MiB] = 128 MiB
    __bf16* xb = (__bf16*)d_ws;
    __bf16* wb = (__bf16*)((char*)d_ws + (size_t)M_DIM * K_DIM * 2);

    xcast_kernel<<<(M_DIM * K_DIM / 8) / 256, 256, 0, stream>>>(x, xb);
    dequant_kernel<<<(N_DIM * (K_DIM / 2) / 4) / 256, 256, 0, stream>>>(qw, scales, zeros, wb);

    dim3 grid(M_DIM / BM, N_DIM / BN);   // (16, 48)
    gemm_kernel<<<grid, 512, 0, stream>>>(xb, wb, bias, out);
}